// Round 4
// baseline (137.274 us; speedup 1.0000x reference)
//
#include <hip/hip_runtime.h>
#include <math.h>

#define NB 4096

#define SCALE_POS 2.0f
#define SCALE_NEG 50.0f
#define THRESH    0.7f
#define MARGIN    0.1f
#define GAMMA     0.3f
#define EPS_SELF  1e-5f

typedef __attribute__((ext_vector_type(8))) short s16x8;
typedef __attribute__((ext_vector_type(4))) float f32x4;
typedef unsigned long long u64;
typedef unsigned int u32;

// Monotone float<->uint key (order-preserving incl +-inf)
__device__ __forceinline__ u32 fkey(float f) {
  u32 u = __float_as_uint(f);
  return (u & 0x80000000u) ? ~u : (u | 0x80000000u);
}
__device__ __forceinline__ float keyf(u32 k) {
  u32 u = (k & 0x80000000u) ? (k & 0x7FFFFFFFu) : ~k;
  return __uint_as_float(u);
}
__device__ __forceinline__ short f2bf(float x) {  // RNE to bf16
  u32 u = __float_as_uint(x);
  return (short)((u + 0x7FFFu + ((u >> 16) & 1u)) >> 16);
}
__device__ __forceinline__ float bf2f(short h) {
  return __uint_as_float(((u32)(unsigned short)h) << 16);
}

#if __has_builtin(__builtin_amdgcn_global_load_lds)
#define HAVE_GLL 1
#endif

// Stage one 1KB fragment: per-lane global src (g already includes +lane*16B),
// wave-uniform LDS base (HW adds lane*16).
__device__ __forceinline__ void gll16(const void* g, void* lds_base) {
#ifdef HAVE_GLL
  __builtin_amdgcn_global_load_lds((const __attribute__((address_space(1))) void*)g,
                                   (__attribute__((address_space(3))) void*)lds_base, 16, 0, 0);
#else
  int lane = threadIdx.x & 63;
  *(s16x8*)((short*)lds_base + lane * 8) = *(const s16x8*)g;
#endif
}

// ---------------------------------------------------------------------------
// K1: fp32 -> split-bf16 into fragment-major F layout.
// F (s16x8 units): frag (tile,s) at (tile*8+s)*64 + lane; s<4 = hi, s>=4 = lo.
// Lane of frag: row tile*16+(l&15), k = s'*32 + (l>>4)*8 (s'=s&3).
__global__ __launch_bounds__(256) void k1_convert(
    const float* __restrict__ emb, short* __restrict__ F,
    u64* __restrict__ minkey, u32* __restrict__ maxkey,
    float* __restrict__ possum, float* __restrict__ negsum) {
  int tid = blockIdx.x * 256 + threadIdx.x;  // 0..65535
  int T = tid >> 8, s = (tid >> 6) & 3, l = tid & 63;
  int r = T * 16 + (l & 15);
  int c = s * 4 + (l >> 4);  // 8-elem chunk index 0..15 within the 128 dims
  const float4* e4 = (const float4*)emb;
  float4 v0 = e4[r * 32 + c * 2];
  float4 v1 = e4[r * 32 + c * 2 + 1];
  float xs[8] = {v0.x, v0.y, v0.z, v0.w, v1.x, v1.y, v1.z, v1.w};
  s16x8 h, lo;
#pragma unroll
  for (int e = 0; e < 8; ++e) {
    short hh = f2bf(xs[e]);
    h[e] = hh;
    lo[e] = f2bf(xs[e] - bf2f(hh));
  }
  ((s16x8*)F)[(T * 8 + s) * 64 + l] = h;       // coalesced
  ((s16x8*)F)[(T * 8 + 4 + s) * 64 + l] = lo;  // coalesced
  if (tid < NB) {
    minkey[tid] = 0xFF800000FFFFFFFFULL;
    maxkey[tid] = 0x007FFFFFu;
    possum[tid] = 0.0f;
    negsum[tid] = 0.0f;
  }
}

// ---------------------------------------------------------------------------
// K2a (pass 1): symmetric Gram min/max. Upper-triangle blocks only (by<=bx).
// 128x128 per block, 4 waves (64x64 quadrants), BK=32 double-buffered LDS via
// global_load_lds. 3-term split-bf16 (HH + HL + LH).
__global__ __launch_bounds__(256) void k2a_pass1(
    const short* __restrict__ F, const int* __restrict__ labels,
    u64* __restrict__ minkey, u32* __restrict__ maxkey) {
  int bx = blockIdx.x, by = blockIdx.y;
  if (by > bx) return;
  __shared__ short Ah[2][8][512], Al[2][8][512], Bh[2][8][512], Bl[2][8][512];
  int tid = threadIdx.x, w = tid >> 6, l = tid & 63;
  int lm16 = l & 15, lg = l >> 4;
  int mtl = (w >> 1) * 4, ntl = (w & 1) * 4;
  const s16x8* F8 = (const s16x8*)F;

  auto stage = [&](int buf, int kb) {
#pragma unroll
    for (int q = 0; q < 2; ++q) {
      int t = w * 2 + q;
      gll16(F8 + ((size_t)(by * 8 + t) * 8 + kb) * 64 + l, &Ah[buf][t][0]);
      gll16(F8 + ((size_t)(by * 8 + t) * 8 + 4 + kb) * 64 + l, &Al[buf][t][0]);
      gll16(F8 + ((size_t)(bx * 8 + t) * 8 + kb) * 64 + l, &Bh[buf][t][0]);
      gll16(F8 + ((size_t)(bx * 8 + t) * 8 + 4 + kb) * 64 + l, &Bl[buf][t][0]);
    }
  };

  f32x4 acc[4][4] = {};
  stage(0, 0);
  __syncthreads();
  for (int kb = 0; kb < 4; ++kb) {
    int cur = kb & 1;
    if (kb < 3) stage(cur ^ 1, kb + 1);
    s16x8 a_h[4], a_l[4], b_h[4], b_l[4];
#pragma unroll
    for (int t = 0; t < 4; ++t) {
      a_h[t] = *(const s16x8*)&Ah[cur][mtl + t][l * 8];
      a_l[t] = *(const s16x8*)&Al[cur][mtl + t][l * 8];
      b_h[t] = *(const s16x8*)&Bh[cur][ntl + t][l * 8];
      b_l[t] = *(const s16x8*)&Bl[cur][ntl + t][l * 8];
    }
#pragma unroll
    for (int ti = 0; ti < 4; ++ti)
#pragma unroll
      for (int tj = 0; tj < 4; ++tj) {
        acc[ti][tj] = __builtin_amdgcn_mfma_f32_16x16x32_bf16(a_h[ti], b_h[tj], acc[ti][tj], 0, 0, 0);
        acc[ti][tj] = __builtin_amdgcn_mfma_f32_16x16x32_bf16(a_h[ti], b_l[tj], acc[ti][tj], 0, 0, 0);
        acc[ti][tj] = __builtin_amdgcn_mfma_f32_16x16x32_bf16(a_l[ti], b_h[tj], acc[ti][tj], 0, 0, 0);
      }
    __syncthreads();
  }

  int mtg0 = by * 8 + mtl, ntg0 = bx * 8 + ntl;
  int4 lab4[4];
#pragma unroll
  for (int ti = 0; ti < 4; ++ti) lab4[ti] = ((const int4*)labels)[(mtg0 + ti) * 4 + lg];
  int labn[4];
#pragma unroll
  for (int tj = 0; tj < 4; ++tj) labn[tj] = labels[(ntg0 + tj) * 16 + lm16];

  // (a) row-anchor reduction (anchors = m rows of this block)
#pragma unroll
  for (int ti = 0; ti < 4; ++ti) {
#pragma unroll
    for (int r = 0; r < 4; ++r) {
      int m = (mtg0 + ti) * 16 + lg * 4 + r;
      int lm = ((const int*)&lab4[ti])[r];
      u64 pk = 0xFF800000FFFFFFFFULL;
      u32 nk = 0x007FFFFFu;
#pragma unroll
      for (int tj = 0; tj < 4; ++tj) {
        int n = (ntg0 + tj) * 16 + lm16;
        float sv = (n == m) ? 1.0f : acc[ti][tj][r];
        if (lm == labn[tj]) {
          if (sv < 1.0f - EPS_SELF) {
            u64 cand = ((u64)fkey(sv) << 32) | (u32)n;
            pk = pk < cand ? pk : cand;
          }
        } else {
          u32 ck = fkey(sv);
          nk = nk > ck ? nk : ck;
        }
      }
#pragma unroll
      for (int d = 1; d < 16; d <<= 1) {
        u64 po = __shfl_xor(pk, d, 64); pk = pk < po ? pk : po;
        u32 no = __shfl_xor(nk, d, 64); nk = nk > no ? nk : no;
      }
      if (lm16 == 0) {
        atomicMin(&minkey[m], pk);
        atomicMax(&maxkey[m], nk);
      }
    }
  }

  // (b) col-anchor reduction (anchors = n cols) — covers lower triangle.
  // Skip for diagonal blocks: (a) already covered the full square there.
  if (by != bx) {
#pragma unroll
    for (int tj = 0; tj < 4; ++tj) {
      int n = (ntg0 + tj) * 16 + lm16;
      int ln = labn[tj];
      u64 pk = 0xFF800000FFFFFFFFULL;
      u32 nk = 0x007FFFFFu;
#pragma unroll
      for (int ti = 0; ti < 4; ++ti) {
#pragma unroll
        for (int r = 0; r < 4; ++r) {
          int m = (mtg0 + ti) * 16 + lg * 4 + r;
          float sv = acc[ti][tj][r];  // m!=n guaranteed (off-diag block)
          int lm = ((const int*)&lab4[ti])[r];
          if (lm == ln) {
            if (sv < 1.0f - EPS_SELF) {
              u64 cand = ((u64)fkey(sv) << 32) | (u32)m;
              pk = pk < cand ? pk : cand;
            }
          } else {
            u32 ck = fkey(sv);
            nk = nk > ck ? nk : ck;
          }
        }
      }
#pragma unroll
      for (int d = 16; d < 64; d <<= 1) {
        u64 po = __shfl_xor(pk, d, 64); pk = pk < po ? pk : po;
        u32 no = __shfl_xor(nk, d, 64); nk = nk > no ? nk : no;
      }
      if (lg == 0) {
        atomicMin(&minkey[n], pk);
        atomicMax(&maxkey[n], nk);
      }
    }
  }
}

// ---------------------------------------------------------------------------
// K3g: decode keys -> row params; gather j-rows' HI fragments into FJ
// (layout: frag (tile,s) at (tile*4+s)*64+lane, s=0..3). One block / 16 rows.
__global__ __launch_bounds__(256) void k3g(
    const short* __restrict__ F,
    const u64* __restrict__ minkey, const u32* __restrict__ maxkey,
    float* __restrict__ minposf, float* __restrict__ maxnegf,
    float* __restrict__ dppA, float* __restrict__ inppA,
    int* __restrict__ validA, short* __restrict__ FJ) {
  __shared__ int s_j[16];
  int tid = threadIdx.x, blk = blockIdx.x;
  if (tid < 16) {
    int i = blk * 16 + tid;
    u64 mk = minkey[i];
    float minpos = keyf((u32)(mk >> 32));
    float maxneg = keyf(maxkey[i]);
    bool valid = (maxneg + MARGIN > minpos);
    int j = valid ? (int)(mk & 0xFFFFFFFFu) : i;
    minposf[i] = minpos;
    maxnegf[i] = maxneg;
    dppA[i] = minpos - 1.0f;  // e_i.d_p = sim_ij - 1 (unit rows)
    inppA[i] = 1.0f / fmaxf(sqrtf(fmaxf(2.0f - 2.0f * minpos, 1e-12f)), 1e-8f);
    validA[i] = valid ? 1 : 0;
    s_j[tid] = j;
  }
  __syncthreads();
  int rrel = tid >> 4, cc = tid & 15;
  int j = s_j[rrel];
  int s = cc >> 2, lp = (cc & 3) * 16;
  ((s16x8*)FJ)[((size_t)(blk * 4 + s)) * 64 + lp + rrel] =
      ((const s16x8*)F)[((size_t)((j >> 4) * 8 + s)) * 64 + lp + (j & 15)];
}

// ---------------------------------------------------------------------------
// K2b (pass 2): dual GEMM recompute, 2-term each (S = HH^T+HL^T, SJ = JH.H^T
// + JH.L^T) + loss epilogue. 128x128 per block, BK=32 dbuf LDS staging.
__global__ __launch_bounds__(256) void k2b_pass2(
    const short* __restrict__ F, const short* __restrict__ FJ,
    const int* __restrict__ labels,
    const float* __restrict__ minposf, const float* __restrict__ maxnegf,
    const float* __restrict__ dppA, const float* __restrict__ inppA,
    float* __restrict__ possum, float* __restrict__ negsum) {
  __shared__ short Eh[2][8][512], Jh[2][8][512], Bh[2][8][512], Bl[2][8][512];
  int tid = threadIdx.x, w = tid >> 6, l = tid & 63;
  int lm16 = l & 15, lg = l >> 4;
  int mtl = (w >> 1) * 4, ntl = (w & 1) * 4;
  int bx = blockIdx.x, by = blockIdx.y;
  const s16x8* F8 = (const s16x8*)F;
  const s16x8* FJ8 = (const s16x8*)FJ;

  auto stage = [&](int buf, int kb) {
#pragma unroll
    for (int q = 0; q < 2; ++q) {
      int t = w * 2 + q;
      gll16(F8 + ((size_t)(by * 8 + t) * 8 + kb) * 64 + l, &Eh[buf][t][0]);
      gll16(FJ8 + ((size_t)(by * 8 + t) * 4 + kb) * 64 + l, &Jh[buf][t][0]);
      gll16(F8 + ((size_t)(bx * 8 + t) * 8 + kb) * 64 + l, &Bh[buf][t][0]);
      gll16(F8 + ((size_t)(bx * 8 + t) * 8 + 4 + kb) * 64 + l, &Bl[buf][t][0]);
    }
  };

  f32x4 accS[4][4] = {}, accJ[4][4] = {};
  stage(0, 0);
  __syncthreads();
  for (int kb = 0; kb < 4; ++kb) {
    int cur = kb & 1;
    if (kb < 3) stage(cur ^ 1, kb + 1);
    s16x8 ah[4], jh[4], bh[4], bl[4];
#pragma unroll
    for (int t = 0; t < 4; ++t) {
      ah[t] = *(const s16x8*)&Eh[cur][mtl + t][l * 8];
      jh[t] = *(const s16x8*)&Jh[cur][mtl + t][l * 8];
      bh[t] = *(const s16x8*)&Bh[cur][ntl + t][l * 8];
      bl[t] = *(const s16x8*)&Bl[cur][ntl + t][l * 8];
    }
#pragma unroll
    for (int ti = 0; ti < 4; ++ti)
#pragma unroll
      for (int tj = 0; tj < 4; ++tj) {
        accS[ti][tj] = __builtin_amdgcn_mfma_f32_16x16x32_bf16(ah[ti], bh[tj], accS[ti][tj], 0, 0, 0);
        accS[ti][tj] = __builtin_amdgcn_mfma_f32_16x16x32_bf16(ah[ti], bl[tj], accS[ti][tj], 0, 0, 0);
        accJ[ti][tj] = __builtin_amdgcn_mfma_f32_16x16x32_bf16(jh[ti], bh[tj], accJ[ti][tj], 0, 0, 0);
        accJ[ti][tj] = __builtin_amdgcn_mfma_f32_16x16x32_bf16(jh[ti], bl[tj], accJ[ti][tj], 0, 0, 0);
      }
    __syncthreads();
  }

  int mtg0 = by * 8 + mtl, ntg0 = bx * 8 + ntl;
  int labn[4];
#pragma unroll
  for (int tj = 0; tj < 4; ++tj) labn[tj] = labels[(ntg0 + tj) * 16 + lm16];

#pragma unroll
  for (int ti = 0; ti < 4; ++ti) {
    int v4 = (mtg0 + ti) * 4 + lg;
    float4 mp4 = ((const float4*)minposf)[v4];
    float4 mx4 = ((const float4*)maxnegf)[v4];
    float4 dp4 = ((const float4*)dppA)[v4];
    float4 ip4 = ((const float4*)inppA)[v4];
    int4 lm4 = ((const int4*)labels)[v4];
#pragma unroll
    for (int r = 0; r < 4; ++r) {
      int m = (mtg0 + ti) * 16 + lg * 4 + r;
      int lm = ((const int*)&lm4)[r];
      float mp = ((const float*)&mp4)[r], mx = ((const float*)&mx4)[r];
      float dpp = ((const float*)&dp4)[r], inpp = ((const float*)&ip4)[r];
      float ps = 0.0f, ns = 0.0f;
#pragma unroll
      for (int tj = 0; tj < 4; ++tj) {
        float sv = accS[ti][tj][r];
        int n = (ntg0 + tj) * 16 + lm16;
        if (lm == labn[tj]) {
          if (n != m && sv < 1.0f - EPS_SELF && sv - MARGIN < mx)
            ps += __expf(-SCALE_POS * (sv - THRESH));
        } else if (sv + MARGIN > mp) {
          float sj = accJ[ti][tj][r];
          float nn = sqrtf(fmaxf(2.0f - 2.0f * sv, 1e-12f));
          float rg = GAMMA * (sj - sv - dpp) * inpp * __builtin_amdgcn_rcpf(nn);
          ns += __expf(SCALE_NEG * (sv - THRESH - rg));
        }
      }
#pragma unroll
      for (int d = 1; d < 16; d <<= 1) {
        ps += __shfl_xor(ps, d, 64);
        ns += __shfl_xor(ns, d, 64);
      }
      if (lm16 == 0) {
        atomicAdd(&possum[m], ps);
        atomicAdd(&negsum[m], ns);
      }
    }
  }
}

// ---------------------------------------------------------------------------
// K5: final row losses + mean. Single block.
__global__ __launch_bounds__(1024) void k5_final(
    const float* __restrict__ possum, const float* __restrict__ negsum,
    const int* __restrict__ validA, float* __restrict__ out) {
  int tid = threadIdx.x;
  float local = 0.0f;
  for (int r = tid; r < NB; r += 1024) {
    if (validA[r])
      local += log1pf(possum[r]) * (1.0f / SCALE_POS) + log1pf(negsum[r]) * (1.0f / SCALE_NEG);
  }
#pragma unroll
  for (int d = 1; d < 64; d <<= 1) local += __shfl_xor(local, d, 64);
  __shared__ float partial[16];
  if ((tid & 63) == 0) partial[tid >> 6] = local;
  __syncthreads();
  if (tid == 0) {
    float t = 0.0f;
#pragma unroll
    for (int q = 0; q < 16; ++q) t += partial[q];
    out[0] = t / (float)NB;
  }
}

// ---------------------------------------------------------------------------
extern "C" void kernel_launch(void* const* d_in, const int* in_sizes, int n_in,
                              void* d_out, int out_size, void* d_ws, size_t ws_size,
                              hipStream_t stream) {
  const float* emb = (const float*)d_in[0];
  const int* labels = (const int*)d_in[1];
  float* out = (float*)d_out;
  char* ws = (char*)d_ws;

  short* F = (short*)ws;                                   // 2 MB (split-bf16, frag-major)
  short* FJ = (short*)(ws + (2 << 20));                    // 1 MB (j-rows, hi only)
  char* base = ws + (3 << 20);
  u64* minkey = (u64*)(base);                              // 32 KB
  u32* maxkey = (u32*)(base + 32768);                      // 16 KB
  float* minposf = (float*)(base + 49152);
  float* maxnegf = (float*)(base + 65536);
  float* dppA = (float*)(base + 81920);
  float* inppA = (float*)(base + 98304);
  int* validA = (int*)(base + 114688);
  float* possum = (float*)(base + 131072);
  float* negsum = (float*)(base + 147456);

  hipLaunchKernelGGL(k1_convert, dim3(NB * 128 / 8 / 256), dim3(256), 0, stream,
                     emb, F, minkey, maxkey, possum, negsum);
  hipLaunchKernelGGL(k2a_pass1, dim3(32, 32), dim3(256), 0, stream,
                     F, labels, minkey, maxkey);
  hipLaunchKernelGGL(k3g, dim3(NB / 16), dim3(256), 0, stream,
                     F, minkey, maxkey, minposf, maxnegf, dppA, inppA, validA, FJ);
  hipLaunchKernelGGL(k2b_pass2, dim3(32, 32), dim3(256), 0, stream,
                     F, FJ, labels, minposf, maxnegf, dppA, inppA, possum, negsum);
  hipLaunchKernelGGL(k5_final, dim3(1), dim3(1024), 0, stream,
                     possum, negsum, validA, out);
}

// Round 5
// 76.848 us; speedup vs baseline: 1.7863x; 1.7863x over previous
//
#include <hip/hip_runtime.h>
#include <math.h>

#define NB 4096

#define SCALE_POS 2.0f
#define SCALE_NEG 50.0f
#define THRESH    0.7f
#define MARGIN    0.1f
#define GAMMA     0.3f
#define EPS_SELF  1e-5f

typedef __attribute__((ext_vector_type(8))) short s16x8;
typedef __attribute__((ext_vector_type(4))) float f32x4;
typedef unsigned long long u64;
typedef unsigned int u32;
typedef unsigned char u8;

// Monotone float<->uint key (order-preserving incl +-inf)
__device__ __forceinline__ u32 fkey(float f) {
  u32 u = __float_as_uint(f);
  return (u & 0x80000000u) ? ~u : (u | 0x80000000u);
}
__device__ __forceinline__ float keyf(u32 k) {
  u32 u = (k & 0x80000000u) ? (k & 0x7FFFFFFFu) : ~k;
  return __uint_as_float(u);
}
__device__ __forceinline__ short f2bf(float x) {  // RNE to bf16
  u32 u = __float_as_uint(x);
  return (short)((u + 0x7FFFu + ((u >> 16) & 1u)) >> 16);
}
__device__ __forceinline__ float bf2f(short h) {
  return __uint_as_float(((u32)(unsigned short)h) << 16);
}

// ---------------------------------------------------------------------------
// K1: fp32 -> split-bf16 into fragment-major F layout; pack labels to u8;
// init reduction keys. 256 blocks x 256 threads.
// F (s16x8 units): frag (T,s) hi at (T*8+s)*64+lane, lo at (T*8+4+s)*64+lane.
// Lane l of frag: row T*16+(l&15), k = s*32 + (l>>4)*8 .. +8.
__global__ __launch_bounds__(256) void k1_convert(
    const float* __restrict__ emb, const int* __restrict__ labels,
    short* __restrict__ F, u8* __restrict__ labu8,
    u64* __restrict__ minkey, u32* __restrict__ maxkey) {
  int tid = blockIdx.x * 256 + threadIdx.x;  // 0..65535
  int T = tid >> 8, s = (tid >> 6) & 3, l = tid & 63;
  int r = T * 16 + (l & 15);
  int c = s * 4 + (l >> 4);  // 8-float chunk index within the 128 dims
  const float4* e4 = (const float4*)emb;
  float4 v0 = e4[r * 32 + c * 2];
  float4 v1 = e4[r * 32 + c * 2 + 1];
  float xs[8] = {v0.x, v0.y, v0.z, v0.w, v1.x, v1.y, v1.z, v1.w};
  s16x8 h, lo;
#pragma unroll
  for (int e = 0; e < 8; ++e) {
    short hh = f2bf(xs[e]);
    h[e] = hh;
    lo[e] = f2bf(xs[e] - bf2f(hh));
  }
  ((s16x8*)F)[(T * 8 + s) * 64 + l] = h;
  ((s16x8*)F)[(T * 8 + 4 + s) * 64 + l] = lo;
  if (tid < 1024) {
    int4 lb = ((const int4*)labels)[tid];
    uchar4 p;
    p.x = (u8)lb.x; p.y = (u8)lb.y; p.z = (u8)lb.z; p.w = (u8)lb.w;
    ((uchar4*)labu8)[tid] = p;
  }
  if (tid < NB) {
    minkey[tid] = 0xFF800000FFFFFFFFULL;  // (+inf key, idx ~0)
    maxkey[tid] = 0x007FFFFFu;            // -inf key
  }
}

// ---------------------------------------------------------------------------
// K2 (pass 1): full Gram via split-bf16 MFMA, NO LDS, fragments direct from
// L2 (coalesced 1KB loads). Block = 4 waves; wave tile 64 rows x 128 cols
// (acc 4x8 frags). Stores sim as bf16 (row-major) + register min/argmin/max
// reduction -> one atomic pair per row per wave.
// grid (NB/256 = 16, NB/128 = 32).
__global__ __launch_bounds__(256) void k2_pass1(
    const short* __restrict__ F, const int* __restrict__ labels,
    short* __restrict__ simh,
    u64* __restrict__ minkey, u32* __restrict__ maxkey) {
  int tid = threadIdx.x, w = tid >> 6, l = tid & 63;
  int lm16 = l & 15, lg = l >> 4;
  int mt0 = blockIdx.y * 8 + (w >> 1) * 4;   // 16-row tile idx (4 tiles)
  int nt0 = blockIdx.x * 16 + (w & 1) * 8;   // 16-col tile idx (8 tiles)
  const s16x8* F8 = (const s16x8*)F;

  f32x4 acc[4][8] = {};
#pragma unroll 1
  for (int s = 0; s < 4; ++s) {
    s16x8 ah[4], al[4], bh[8], bl[8];
#pragma unroll
    for (int t = 0; t < 4; ++t) {
      int ia = ((mt0 + t) * 8 + s) * 64 + l;
      ah[t] = F8[ia];
      al[t] = F8[ia + 256];  // lo plane: +4*64
    }
#pragma unroll
    for (int t = 0; t < 8; ++t) {
      int ib = ((nt0 + t) * 8 + s) * 64 + l;
      bh[t] = F8[ib];
      bl[t] = F8[ib + 256];
    }
#pragma unroll
    for (int ti = 0; ti < 4; ++ti)
#pragma unroll
      for (int tj = 0; tj < 8; ++tj) {
        acc[ti][tj] = __builtin_amdgcn_mfma_f32_16x16x32_bf16(ah[ti], bh[tj], acc[ti][tj], 0, 0, 0);
        acc[ti][tj] = __builtin_amdgcn_mfma_f32_16x16x32_bf16(ah[ti], bl[tj], acc[ti][tj], 0, 0, 0);
        acc[ti][tj] = __builtin_amdgcn_mfma_f32_16x16x32_bf16(al[ti], bh[tj], acc[ti][tj], 0, 0, 0);
      }
  }

  int labn[8];
#pragma unroll
  for (int tj = 0; tj < 8; ++tj) labn[tj] = labels[(nt0 + tj) * 16 + lm16];

#pragma unroll
  for (int ti = 0; ti < 4; ++ti) {
    int4 lm4 = ((const int4*)labels)[(mt0 + ti) * 4 + lg];
#pragma unroll
    for (int r = 0; r < 4; ++r) {
      int m = (mt0 + ti) * 16 + lg * 4 + r;
      int lm = ((const int*)&lm4)[r];
      size_t rowbase = (size_t)m * NB;
      u64 pk = 0xFF800000FFFFFFFFULL;
      u32 nk = 0x007FFFFFu;
#pragma unroll
      for (int tj = 0; tj < 8; ++tj) {
        float sv = acc[ti][tj][r];
        int n = (nt0 + tj) * 16 + lm16;
        if (n == m) sv = 1.0f;  // exact diagonal; excluded by value gate
        simh[rowbase + n] = f2bf(sv);
        if (lm == labn[tj]) {
          if (sv < 1.0f - EPS_SELF) {
            u64 cand = ((u64)fkey(sv) << 32) | (u32)n;
            pk = pk < cand ? pk : cand;
          }
        } else {
          u32 ck = fkey(sv);
          nk = nk > ck ? nk : ck;
        }
      }
#pragma unroll
      for (int d = 1; d < 16; d <<= 1) {
        u64 po = __shfl_xor(pk, d, 64); pk = pk < po ? pk : po;
        u32 no = __shfl_xor(nk, d, 64); nk = nk > no ? nk : no;
      }
      if (lm16 == 0) {
        atomicMin(&minkey[m], pk);
        atomicMax(&maxkey[m], nk);
      }
    }
  }
}

// ---------------------------------------------------------------------------
// K3: decode keys -> row params (identities from unit-norm rows).
__global__ __launch_bounds__(256) void k3_prep(
    const u64* __restrict__ minkey, const u32* __restrict__ maxkey,
    float* __restrict__ minposf, float* __restrict__ maxnegf,
    float* __restrict__ dppA, float* __restrict__ inppA,
    int* __restrict__ jarr, int* __restrict__ validA) {
  int i = blockIdx.x * 256 + threadIdx.x;
  u64 mk = minkey[i];
  float minpos = keyf((u32)(mk >> 32));
  float maxneg = keyf(maxkey[i]);
  bool valid = (maxneg + MARGIN > minpos);
  int j = valid ? (int)(mk & 0xFFFFFFFFu) : i;
  minposf[i] = minpos;
  maxnegf[i] = maxneg;
  dppA[i] = minpos - 1.0f;  // e_i.d_p = sim_ij - 1
  inppA[i] = 1.0f / fmaxf(sqrtf(fmaxf(2.0f - 2.0f * minpos, 1e-12f)), 1e-8f);
  jarr[i] = j;
  validA[i] = valid ? 1 : 0;
}

// ---------------------------------------------------------------------------
// K4: per-anchor streaming pass over bf16 sim[i,:], sim[j,:] + u8 labels.
// One block (256 thr) per row; 16B/lane loads.
__global__ __launch_bounds__(256) void k4_row(
    const short* __restrict__ simh, const u8* __restrict__ labu8,
    const float* __restrict__ minposf, const float* __restrict__ maxnegf,
    const float* __restrict__ dppA, const float* __restrict__ inppA,
    const int* __restrict__ jarr, const int* __restrict__ validA,
    float* __restrict__ rowloss) {
  int i = blockIdx.x, tid = threadIdx.x;
  if (!validA[i]) {
    if (tid == 0) rowloss[i] = 0.0f;
    return;
  }
  int j = jarr[i];
  float mp = minposf[i], mx = maxnegf[i];
  float dpp = dppA[i], inpp = inppA[i];
  int lm = (int)labu8[i];
  const s16x8* sI = (const s16x8*)(simh + (size_t)i * NB);
  const s16x8* sJ = (const s16x8*)(simh + (size_t)j * NB);
  const u64* L8 = (const u64*)labu8;
  float ps = 0.0f, ns = 0.0f;
#pragma unroll 1
  for (int c = tid; c < NB / 8; c += 256) {  // 2 iterations
    s16x8 a = sI[c];
    s16x8 b = sJ[c];
    u64 lab = L8[c];
#pragma unroll
    for (int e = 0; e < 8; ++e) {
      float s = bf2f(a[e]);
      int ln = (int)((lab >> (8 * e)) & 255u);
      if (ln == lm) {
        if (s < 1.0f - EPS_SELF && s - MARGIN < mx)
          ps += __expf(-SCALE_POS * (s - THRESH));
      } else if (s + MARGIN > mp) {
        float sj = bf2f(b[e]);
        float nn = fmaxf(sqrtf(fmaxf(2.0f - 2.0f * s, 1e-12f)), 1e-8f);
        float rg = GAMMA * (sj - s - dpp) * inpp * __builtin_amdgcn_rcpf(nn);
        ns += __expf(SCALE_NEG * (s - THRESH - rg));
      }
    }
  }
#pragma unroll
  for (int d = 1; d < 64; d <<= 1) {
    ps += __shfl_xor(ps, d, 64);
    ns += __shfl_xor(ns, d, 64);
  }
  __shared__ float redp[4], redn[4];
  if ((tid & 63) == 0) {
    redp[tid >> 6] = ps;
    redn[tid >> 6] = ns;
  }
  __syncthreads();
  if (tid == 0) {
    float tp = redp[0] + redp[1] + redp[2] + redp[3];
    float tn = redn[0] + redn[1] + redn[2] + redn[3];
    rowloss[i] = log1pf(tp) * (1.0f / SCALE_POS) + log1pf(tn) * (1.0f / SCALE_NEG);
  }
}

// ---------------------------------------------------------------------------
// K5: mean over rows. Single block.
__global__ __launch_bounds__(1024) void k5_final(
    const float* __restrict__ rowloss, float* __restrict__ out) {
  int tid = threadIdx.x;
  float local = 0.0f;
  for (int r = tid; r < NB; r += 1024) local += rowloss[r];
#pragma unroll
  for (int d = 1; d < 64; d <<= 1) local += __shfl_xor(local, d, 64);
  __shared__ float partial[16];
  if ((tid & 63) == 0) partial[tid >> 6] = local;
  __syncthreads();
  if (tid == 0) {
    float t = 0.0f;
#pragma unroll
    for (int q = 0; q < 16; ++q) t += partial[q];
    out[0] = t / (float)NB;
  }
}

// ---------------------------------------------------------------------------
extern "C" void kernel_launch(void* const* d_in, const int* in_sizes, int n_in,
                              void* d_out, int out_size, void* d_ws, size_t ws_size,
                              hipStream_t stream) {
  const float* emb = (const float*)d_in[0];
  const int* labels = (const int*)d_in[1];
  float* out = (float*)d_out;
  char* ws = (char*)d_ws;

  short* simh = (short*)ws;                               // 32 MB bf16 sim
  short* F = (short*)(ws + ((size_t)NB * NB * 2));        // 2 MB split-bf16 frags
  char* base = ws + ((size_t)NB * NB * 2) + (2 << 20);
  u64* minkey = (u64*)(base);                             // 32 KB
  u32* maxkey = (u32*)(base + 32768);                     // 16 KB
  float* minposf = (float*)(base + 49152);
  float* maxnegf = (float*)(base + 65536);
  float* dppA = (float*)(base + 81920);
  float* inppA = (float*)(base + 98304);
  int* jarr = (int*)(base + 114688);
  int* validA = (int*)(base + 131072);
  float* rowloss = (float*)(base + 147456);
  u8* labu8 = (u8*)(base + 163840);                       // 4 KB

  hipLaunchKernelGGL(k1_convert, dim3(256), dim3(256), 0, stream,
                     emb, labels, F, labu8, minkey, maxkey);
  hipLaunchKernelGGL(k2_pass1, dim3(NB / 256, NB / 128), dim3(256), 0, stream,
                     F, labels, simh, minkey, maxkey);
  hipLaunchKernelGGL(k3_prep, dim3(NB / 256), dim3(256), 0, stream,
                     minkey, maxkey, minposf, maxnegf, dppA, inppA, jarr, validA);
  hipLaunchKernelGGL(k4_row, dim3(NB), dim3(256), 0, stream,
                     simh, labu8, minposf, maxnegf, dppA, inppA, jarr, validA, rowloss);
  hipLaunchKernelGGL(k5_final, dim3(1), dim3(1024), 0, stream, rowloss, out);
}